// Round 4
// baseline (287.823 us; speedup 1.0000x reference)
//
#include <hip/hip_runtime.h>

// ---- problem constants ----
constexpr int Bc   = 4;
constexpr int Qlen = 2048;
constexpr int Klen = 2048;
constexpr int Dm   = 512;
constexpr int Hh   = 8;
constexpr int HDim = 64;

typedef __attribute__((ext_vector_type(8))) short short8;       // 8x16-bit storage
typedef __attribute__((ext_vector_type(8))) _Float16 half8;     // fp16 MFMA frag
typedef __attribute__((ext_vector_type(4))) float f32x4;

__device__ __forceinline__ f32x4 MFMA16(short8 a, short8 b, f32x4 c) {
  return __builtin_amdgcn_mfma_f32_16x16x32_f16(
      __builtin_bit_cast(half8, a), __builtin_bit_cast(half8, b), c, 0, 0, 0);
}

__device__ __forceinline__ void gload_lds16(const void* g, void* l) {
  __builtin_amdgcn_global_load_lds(
      (const __attribute__((address_space(1))) void*)g,
      (__attribute__((address_space(3))) void*)l, 16, 0, 0);
}

__device__ __forceinline__ unsigned short f2h(float f) {   // f32 -> fp16 RNE
  _Float16 h = (_Float16)f;
  return __builtin_bit_cast(unsigned short, h);
}

// ============================================================
// f32 -> fp16 conversion (weights), 4 elems/thread
// ============================================================
__global__ __launch_bounds__(256) void cvt_f32_f16(
    const float* __restrict__ src, unsigned short* __restrict__ dst, int n) {
  int i = (blockIdx.x * 256 + threadIdx.x) * 4;
  if (i + 3 < n) {
    float4 x = *(const float4*)(src + i);
    dst[i + 0] = f2h(x.x);
    dst[i + 1] = f2h(x.y);
    dst[i + 2] = f2h(x.z);
    dst[i + 3] = f2h(x.w);
  }
}

// ============================================================
// Fused QKV projection: C[m,n] = X[m,:] . W[n,:]  (X @ W^T)
// X is fp32 (converted to fp16 in-flight during LDS staging);
// W is pre-converted fp16 (global_load_lds width 16).
// n in [0,1536): seg 0=Q,1=K,2=V. seg0/1 -> (B,H,seq,HD); seg2 -> V^T.
// ============================================================
__global__ __launch_bounds__(256) void gemm_qkv(
    const float* __restrict__ q_in,
    const float* __restrict__ k_in,
    const float* __restrict__ v_in,
    const unsigned short* __restrict__ Wqh,
    const unsigned short* __restrict__ Wkh,
    const unsigned short* __restrict__ Wvh,
    unsigned short* __restrict__ Qp,
    unsigned short* __restrict__ Kp,
    unsigned short* __restrict__ Vt) {
  __shared__ unsigned short As[128 * 32];
  __shared__ unsigned short Bs[128 * 32];
  const int tid = threadIdx.x;
  const int w = tid >> 6, l = tid & 63;
  const int quad = l >> 4, l15 = l & 15;
  const int m0 = blockIdx.x * 128;
  const int n0 = blockIdx.y * 128;
  const int seg = n0 >> 9;
  const int f0  = n0 & 511;
  const float* A = (seg == 0) ? q_in : (seg == 1) ? k_in : v_in;
  const unsigned short* W = (seg == 0) ? Wqh : (seg == 1) ? Wkh : Wvh;

  f32x4 acc[4][4] = {};
  const int lrow = l >> 2;        // 0..15
  const int lcol = (l & 3) * 8;   // element col in 32-wide k-slab
  const int wm = (w >> 1) * 64, wn = (w & 1) * 64;

  for (int kk = 0; kk < 512; kk += 32) {
#pragma unroll
    for (int i = 0; i < 2; ++i) {
      int row = w * 32 + i * 16 + lrow;
      // A: fp32 load + convert + LDS write
      const float* ap = A + (size_t)(m0 + row) * 512 + kk + lcol;
      float4 x0 = *(const float4*)(ap);
      float4 x1 = *(const float4*)(ap + 4);
      union { short8 v; unsigned short u[8]; } t;
      t.u[0] = f2h(x0.x); t.u[1] = f2h(x0.y);
      t.u[2] = f2h(x0.z); t.u[3] = f2h(x0.w);
      t.u[4] = f2h(x1.x); t.u[5] = f2h(x1.y);
      t.u[6] = f2h(x1.z); t.u[7] = f2h(x1.w);
      *(short8*)&As[row * 32 + lcol] = t.v;
      // W: fp16, async direct-to-LDS
      gload_lds16(W + (size_t)(f0 + row) * 512 + kk + lcol, &Bs[row * 32 + lcol]);
    }
    __syncthreads();
    short8 af[4], bf[4];
#pragma unroll
    for (int t = 0; t < 4; ++t)
      af[t] = *(const short8*)&As[(wm + t * 16 + l15) * 32 + quad * 8];
#pragma unroll
    for (int t = 0; t < 4; ++t)
      bf[t] = *(const short8*)&Bs[(wn + t * 16 + l15) * 32 + quad * 8];
#pragma unroll
    for (int mt = 0; mt < 4; ++mt)
#pragma unroll
      for (int nt = 0; nt < 4; ++nt)
        acc[mt][nt] = MFMA16(af[mt], bf[nt], acc[mt][nt]);
    __syncthreads();
  }
  // epilogue: C/D layout col=lane&15, row=quad*4+reg (dtype-independent)
#pragma unroll
  for (int mt = 0; mt < 4; ++mt)
#pragma unroll
    for (int nt = 0; nt < 4; ++nt)
#pragma unroll
      for (int r = 0; r < 4; ++r) {
        int m  = m0 + wm + mt * 16 + quad * 4 + r;
        int nn = f0 + wn + nt * 16 + l15;
        int b = m >> 11, qq = m & 2047;
        int h = nn >> 6, hd = nn & 63;
        unsigned short val = f2h(acc[mt][nt][r]);
        if (seg == 0)
          Qp[(((size_t)(b * Hh + h)) * Qlen + qq) * HDim + hd] = val;
        else if (seg == 1)
          Kp[(((size_t)(b * Hh + h)) * Qlen + qq) * HDim + hd] = val;
        else  // V stored transposed: (B,H,HD,K)
          Vt[(((size_t)(b * Hh + h)) * HDim + hd) * Klen + qq] = val;
      }
}

// ============================================================
// Output projection: d_out[m,n] = Oa[m,:] . Wo[n,:], fp32 row-major out
// ============================================================
__global__ __launch_bounds__(256) void gemm_out(
    const unsigned short* __restrict__ Oa,
    const unsigned short* __restrict__ Woh,
    float* __restrict__ out) {
  __shared__ unsigned short As[128 * 32];
  __shared__ unsigned short Bs[128 * 32];
  const int tid = threadIdx.x;
  const int w = tid >> 6, l = tid & 63;
  const int quad = l >> 4, l15 = l & 15;
  const int m0 = blockIdx.x * 128;
  const int n0 = blockIdx.y * 128;

  f32x4 acc[4][4] = {};
  const int lrow = l >> 2;
  const int lcol = (l & 3) * 8;
  const int wm = (w >> 1) * 64, wn = (w & 1) * 64;

  for (int kk = 0; kk < 512; kk += 32) {
#pragma unroll
    for (int i = 0; i < 2; ++i) {
      int row = w * 32 + i * 16 + lrow;
      gload_lds16(Oa + (size_t)(m0 + row) * 512 + kk + lcol, &As[row * 32 + lcol]);
      gload_lds16(Woh + (size_t)(n0 + row) * 512 + kk + lcol, &Bs[row * 32 + lcol]);
    }
    __syncthreads();
    short8 af[4], bf[4];
#pragma unroll
    for (int t = 0; t < 4; ++t)
      af[t] = *(const short8*)&As[(wm + t * 16 + l15) * 32 + quad * 8];
#pragma unroll
    for (int t = 0; t < 4; ++t)
      bf[t] = *(const short8*)&Bs[(wn + t * 16 + l15) * 32 + quad * 8];
#pragma unroll
    for (int mt = 0; mt < 4; ++mt)
#pragma unroll
      for (int nt = 0; nt < 4; ++nt)
        acc[mt][nt] = MFMA16(af[mt], bf[nt], acc[mt][nt]);
    __syncthreads();
  }
#pragma unroll
  for (int mt = 0; mt < 4; ++mt)
#pragma unroll
    for (int nt = 0; nt < 4; ++nt)
#pragma unroll
      for (int r = 0; r < 4; ++r) {
        int m  = m0 + wm + mt * 16 + quad * 4 + r;
        int nn = n0 + wn + nt * 16 + l15;
        out[(size_t)m * 512 + nn] = acc[mt][nt][r];   // fp32 store
      }
}

// ============================================================
// Flash attention: 1 block = 128 Q-rows of one (b,h). 4 waves x 32 rows.
// fp16 operands; softmax state in f32. Mask as finite additive bias
// (-30000): exp2f underflows to exactly 0, matching ref's -1e30.
// ============================================================
__global__ __launch_bounds__(256) void attn(
    const unsigned short* __restrict__ Qp,
    const unsigned short* __restrict__ Kp,
    const unsigned short* __restrict__ Vt,
    const int* __restrict__ mask,
    unsigned short* __restrict__ Oa) {
  __shared__ unsigned short Qs[128 * 72];
  __shared__ unsigned short Ks[64 * 72];
  __shared__ unsigned short Vs[64 * 72];
  __shared__ unsigned short Ps[4][32 * 72];
  __shared__ float bias_s[64];

  const int tid = threadIdx.x;
  const int w = tid >> 6, l = tid & 63;
  const int quad = l >> 4, l15 = l & 15;
  const int bid = blockIdx.x;
  const int bh = bid & 31;      // same bh -> same XCD (bid%8 == bh%8)
  const int qt = bid >> 5;
  const int b = bh >> 3, h = bh & 7;

  // ---- stage Q tile (128x64) into padded LDS ----
  const unsigned short* qptr = Qp + ((size_t)bh * Qlen + qt * 128) * HDim;
#pragma unroll
  for (int i = 0; i < 4; ++i) {
    int g = i * 256 + tid;
    int row = g >> 3, c8 = g & 7;
    *(uint4*)&Qs[row * 72 + c8 * 8] = *(const uint4*)(qptr + (size_t)row * 64 + c8 * 8);
  }

  f32x4 o[2][4] = {};
  float m_run[2][4], l_run[2][4];
#pragma unroll
  for (int s = 0; s < 2; ++s)
#pragma unroll
    for (int r = 0; r < 4; ++r) { m_run[s][r] = -1.0e6f; l_run[s][r] = 0.f; }

  constexpr float SCALE = 0.125f;             // 1/sqrt(64)
  constexpr float LOG2E = 1.4426950408889634f;
  constexpr float MASKB = -30000.0f;          // finite; exp2f -> exact 0

  for (int kt = 0; kt < Klen / 64; ++kt) {
    __syncthreads();   // prev tile's reads done; (kt==0) Q writes visible
#pragma unroll
    for (int i = 0; i < 2; ++i) {
      int g = i * 256 + tid;
      int row = g >> 3, c8 = g & 7;
      *(uint4*)&Ks[row * 72 + c8 * 8] =
          *(const uint4*)(Kp + ((size_t)bh * Klen + kt * 64 + row) * 64 + c8 * 8);
      *(uint4*)&Vs[row * 72 + c8 * 8] =
          *(const uint4*)(Vt + ((size_t)bh * HDim + row) * Klen + kt * 64 + c8 * 8);
    }
    if (tid < 64)
      bias_s[tid] = (mask[b * Klen + kt * 64 + tid] == 0) ? MASKB : 0.f;
    __syncthreads();

    // ---- S = Q K^T ----
    short8 aq[2][2];
#pragma unroll
    for (int s = 0; s < 2; ++s)
#pragma unroll
      for (int k2 = 0; k2 < 2; ++k2)
        aq[s][k2] = *(const short8*)&Qs[(w * 32 + s * 16 + l15) * 72 + (k2 * 4 + quad) * 8];
    f32x4 sv[2][4];
#pragma unroll
    for (int ct = 0; ct < 4; ++ct) {
      const short8 bk0 = *(const short8*)&Ks[(ct * 16 + l15) * 72 + quad * 8];
      const short8 bk1 = *(const short8*)&Ks[(ct * 16 + l15) * 72 + (4 + quad) * 8];
#pragma unroll
      for (int s = 0; s < 2; ++s) {
        f32x4 a = {};
        a = MFMA16(aq[s][0], bk0, a);
        a = MFMA16(aq[s][1], bk1, a);
        sv[s][ct] = a;
      }
    }
    float bb4[4];
#pragma unroll
    for (int ct = 0; ct < 4; ++ct) bb4[ct] = bias_s[ct * 16 + l15];

    // ---- online softmax (row i = s*16 + quad*4 + r; cols = ct*16+l15) ----
#pragma unroll
    for (int s = 0; s < 2; ++s) {
#pragma unroll
      for (int ct = 0; ct < 4; ++ct)
#pragma unroll
        for (int r = 0; r < 4; ++r)
          sv[s][ct][r] = sv[s][ct][r] * SCALE + bb4[ct];
#pragma unroll
      for (int r = 0; r < 4; ++r) {
        float mx = fmaxf(fmaxf(sv[s][0][r], sv[s][1][r]),
                         fmaxf(sv[s][2][r], sv[s][3][r]));
#pragma unroll
        for (int off = 1; off < 16; off <<= 1)
          mx = fmaxf(mx, __shfl_xor(mx, off, 16));
        float mnew  = fmaxf(m_run[s][r], mx);
        float alpha = exp2f((m_run[s][r] - mnew) * LOG2E);
        float rs = 0.f;
#pragma unroll
        for (int ct = 0; ct < 4; ++ct) {
          float p = exp2f((sv[s][ct][r] - mnew) * LOG2E);
          sv[s][ct][r] = p;
          rs += p;
        }
#pragma unroll
        for (int off = 1; off < 16; off <<= 1)
          rs += __shfl_xor(rs, off, 16);
        l_run[s][r] = l_run[s][r] * alpha + rs;
        m_run[s][r] = mnew;
#pragma unroll
        for (int ctd = 0; ctd < 4; ++ctd) o[s][ctd][r] *= alpha;
      }
      // P (C-layout) -> wave-private LDS, re-read in A-layout
#pragma unroll
      for (int ct = 0; ct < 4; ++ct)
#pragma unroll
        for (int r = 0; r < 4; ++r)
          Ps[w][(s * 16 + quad * 4 + r) * 72 + ct * 16 + l15] = f2h(sv[s][ct][r]);
    }

    // ---- O += P V  (within-wave LDS ordering; no barrier needed) ----
#pragma unroll
    for (int s = 0; s < 2; ++s) {
      const short8 ap0 = *(const short8*)&Ps[w][(s * 16 + l15) * 72 + quad * 8];
      const short8 ap1 = *(const short8*)&Ps[w][(s * 16 + l15) * 72 + (4 + quad) * 8];
#pragma unroll
      for (int ctd = 0; ctd < 4; ++ctd) {
        const short8 bv0 = *(const short8*)&Vs[(ctd * 16 + l15) * 72 + quad * 8];
        const short8 bv1 = *(const short8*)&Vs[(ctd * 16 + l15) * 72 + (4 + quad) * 8];
        o[s][ctd] = MFMA16(ap0, bv0, o[s][ctd]);
        o[s][ctd] = MFMA16(ap1, bv1, o[s][ctd]);
      }
    }
  }

  // ---- epilogue: Oa (B, Q, D) fp16, feature = h*64 + d ----
#pragma unroll
  for (int s = 0; s < 2; ++s)
#pragma unroll
    for (int ctd = 0; ctd < 4; ++ctd)
#pragma unroll
      for (int r = 0; r < 4; ++r) {
        int qq = qt * 128 + w * 32 + s * 16 + quad * 4 + r;
        float v = o[s][ctd][r] / l_run[s][r];
        Oa[((size_t)(b * Qlen) + qq) * Dm + h * 64 + ctd * 16 + l15] = f2h(v);
      }
}

extern "C" void kernel_launch(void* const* d_in, const int* in_sizes, int n_in,
                              void* d_out, int out_size, void* d_ws, size_t ws_size,
                              hipStream_t stream) {
  const float* q  = (const float*)d_in[0];
  const float* k  = (const float*)d_in[1];
  const float* v  = (const float*)d_in[2];
  const float* Wq = (const float*)d_in[3];
  const float* Wk = (const float*)d_in[4];
  const float* Wv = (const float*)d_in[5];
  const float* Wo = (const float*)d_in[6];
  const int*  msk = (const int*)d_in[7];
  float* out = (float*)d_out;

  char* ws = (char*)d_ws;
  const size_t SEG = (size_t)Bc * Hh * Qlen * HDim * sizeof(unsigned short); // 8 MB
  const size_t WSEG = (size_t)Dm * Dm * sizeof(unsigned short);              // 0.5 MB
  unsigned short* Qp  = (unsigned short*)(ws);
  unsigned short* Kp  = (unsigned short*)(ws + SEG);
  unsigned short* Vt  = (unsigned short*)(ws + 2 * SEG);
  unsigned short* Oa  = (unsigned short*)(ws + 3 * SEG);
  unsigned short* Wqh = (unsigned short*)(ws + 4 * SEG);
  unsigned short* Wkh = (unsigned short*)(ws + 4 * SEG + WSEG);
  unsigned short* Wvh = (unsigned short*)(ws + 4 * SEG + 2 * WSEG);
  unsigned short* Woh = (unsigned short*)(ws + 4 * SEG + 3 * WSEG);

  const int wn = Dm * Dm;                       // 262144
  const int cblk = wn / (256 * 4);              // 256 blocks
  hipLaunchKernelGGL(cvt_f32_f16, dim3(cblk), dim3(256), 0, stream, Wq, Wqh, wn);
  hipLaunchKernelGGL(cvt_f32_f16, dim3(cblk), dim3(256), 0, stream, Wk, Wkh, wn);
  hipLaunchKernelGGL(cvt_f32_f16, dim3(cblk), dim3(256), 0, stream, Wv, Wvh, wn);
  hipLaunchKernelGGL(cvt_f32_f16, dim3(cblk), dim3(256), 0, stream, Wo, Woh, wn);

  hipLaunchKernelGGL(gemm_qkv, dim3(64, 12), dim3(256), 0, stream,
                     q, k, v, Wqh, Wkh, Wvh, Qp, Kp, Vt);
  hipLaunchKernelGGL(attn, dim3(512), dim3(256), 0, stream, Qp, Kp, Vt, msk, Oa);
  hipLaunchKernelGGL(gemm_out, dim3(64, 4), dim3(256), 0, stream, Oa, Woh, out);
}

// Round 5
// 270.729 us; speedup vs baseline: 1.0631x; 1.0631x over previous
//
#include <hip/hip_runtime.h>

// ---- problem constants ----
constexpr int Bc   = 4;
constexpr int Qlen = 2048;
constexpr int Klen = 2048;
constexpr int Dm   = 512;
constexpr int Hh   = 8;
constexpr int HDim = 64;

typedef __attribute__((ext_vector_type(8))) short short8;       // 8x16-bit storage
typedef __attribute__((ext_vector_type(8))) _Float16 half8;     // fp16 MFMA frag
typedef __attribute__((ext_vector_type(4))) float f32x4;

__device__ __forceinline__ f32x4 MFMA16(short8 a, short8 b, f32x4 c) {
  return __builtin_amdgcn_mfma_f32_16x16x32_f16(
      __builtin_bit_cast(half8, a), __builtin_bit_cast(half8, b), c, 0, 0, 0);
}

__device__ __forceinline__ void gload_lds16(const void* g, void* l) {
  __builtin_amdgcn_global_load_lds(
      (const __attribute__((address_space(1))) void*)g,
      (__attribute__((address_space(3))) void*)l, 16, 0, 0);
}

__device__ __forceinline__ unsigned short f2h(float f) {   // f32 -> fp16 RNE
  _Float16 h = (_Float16)f;
  return __builtin_bit_cast(unsigned short, h);
}

// ============================================================
// f32 -> fp16 conversion (weights), 4 elems/thread
// ============================================================
__global__ __launch_bounds__(256) void cvt_f32_f16(
    const float* __restrict__ src, unsigned short* __restrict__ dst, int n) {
  int i = (blockIdx.x * 256 + threadIdx.x) * 4;
  if (i + 3 < n) {
    float4 x = *(const float4*)(src + i);
    dst[i + 0] = f2h(x.x);
    dst[i + 1] = f2h(x.y);
    dst[i + 2] = f2h(x.z);
    dst[i + 3] = f2h(x.w);
  }
}

// ============================================================
// Fused QKV projection: C[m,n] = X[m,:] . W[n,:]  (X @ W^T)
// X fp32 (converted to fp16 in-flight during LDS staging);
// W pre-converted fp16 (global_load_lds width 16).
// All segs write normal (B,H,seq,HD) layout (coalesced-ish 2B stores).
// ============================================================
__global__ __launch_bounds__(256) void gemm_qkv(
    const float* __restrict__ q_in,
    const float* __restrict__ k_in,
    const float* __restrict__ v_in,
    const unsigned short* __restrict__ Wqh,
    const unsigned short* __restrict__ Wkh,
    const unsigned short* __restrict__ Wvh,
    unsigned short* __restrict__ Qp,
    unsigned short* __restrict__ Kp,
    unsigned short* __restrict__ Vp) {
  __shared__ unsigned short As[128 * 32];
  __shared__ unsigned short Bs[128 * 32];
  const int tid = threadIdx.x;
  const int w = tid >> 6, l = tid & 63;
  const int quad = l >> 4, l15 = l & 15;
  const int m0 = blockIdx.x * 128;
  const int n0 = blockIdx.y * 128;
  const int seg = n0 >> 9;
  const int f0  = n0 & 511;
  const float* A = (seg == 0) ? q_in : (seg == 1) ? k_in : v_in;
  const unsigned short* W = (seg == 0) ? Wqh : (seg == 1) ? Wkh : Wvh;
  unsigned short* dst = (seg == 0) ? Qp : (seg == 1) ? Kp : Vp;

  f32x4 acc[4][4] = {};
  const int lrow = l >> 2;        // 0..15
  const int lcol = (l & 3) * 8;   // element col in 32-wide k-slab
  const int wm = (w >> 1) * 64, wn = (w & 1) * 64;

  for (int kk = 0; kk < 512; kk += 32) {
#pragma unroll
    for (int i = 0; i < 2; ++i) {
      int row = w * 32 + i * 16 + lrow;
      const float* ap = A + (size_t)(m0 + row) * 512 + kk + lcol;
      float4 x0 = *(const float4*)(ap);
      float4 x1 = *(const float4*)(ap + 4);
      union { short8 v; unsigned short u[8]; } t;
      t.u[0] = f2h(x0.x); t.u[1] = f2h(x0.y);
      t.u[2] = f2h(x0.z); t.u[3] = f2h(x0.w);
      t.u[4] = f2h(x1.x); t.u[5] = f2h(x1.y);
      t.u[6] = f2h(x1.z); t.u[7] = f2h(x1.w);
      *(short8*)&As[row * 32 + lcol] = t.v;
      gload_lds16(W + (size_t)(f0 + row) * 512 + kk + lcol, &Bs[row * 32 + lcol]);
    }
    __syncthreads();
    short8 af[4], bf[4];
#pragma unroll
    for (int t = 0; t < 4; ++t)
      af[t] = *(const short8*)&As[(wm + t * 16 + l15) * 32 + quad * 8];
#pragma unroll
    for (int t = 0; t < 4; ++t)
      bf[t] = *(const short8*)&Bs[(wn + t * 16 + l15) * 32 + quad * 8];
#pragma unroll
    for (int mt = 0; mt < 4; ++mt)
#pragma unroll
      for (int nt = 0; nt < 4; ++nt)
        acc[mt][nt] = MFMA16(af[mt], bf[nt], acc[mt][nt]);
    __syncthreads();
  }
  // epilogue: C/D layout col=lane&15, row=quad*4+reg
#pragma unroll
  for (int mt = 0; mt < 4; ++mt)
#pragma unroll
    for (int nt = 0; nt < 4; ++nt)
#pragma unroll
      for (int r = 0; r < 4; ++r) {
        int m  = m0 + wm + mt * 16 + quad * 4 + r;
        int nn = f0 + wn + nt * 16 + l15;
        int b = m >> 11, qq = m & 2047;
        int h = nn >> 6, hd = nn & 63;
        dst[(((size_t)(b * Hh + h)) * Qlen + qq) * HDim + hd] = f2h(acc[mt][nt][r]);
      }
}

// ============================================================
// V transpose: Vp (B,H,K,HD) -> Vt (B,H,HD,K), 64x64 tiles via LDS
// ============================================================
__global__ __launch_bounds__(256) void transpose_v(
    const unsigned short* __restrict__ Vp, unsigned short* __restrict__ Vt) {
  __shared__ unsigned short t[64 * 72];
  const int bh = blockIdx.y, jt = blockIdx.x;
  const int tid = threadIdx.x;
#pragma unroll
  for (int i = 0; i < 2; ++i) {
    int g = i * 256 + tid;
    int j = g >> 3, c8 = g & 7;
    *(uint4*)&t[j * 72 + c8 * 8] =
        *(const uint4*)(Vp + ((size_t)bh * Klen + jt * 64 + j) * 64 + c8 * 8);
  }
  __syncthreads();
#pragma unroll
  for (int i = 0; i < 2; ++i) {
    int g = i * 256 + tid;
    int d = g >> 3, j8 = g & 7;
    unsigned short tmp[8];
#pragma unroll
    for (int kx = 0; kx < 8; ++kx) tmp[kx] = t[(j8 * 8 + kx) * 72 + d];
    *(uint4*)(Vt + ((size_t)bh * HDim + d) * Klen + jt * 64 + j8 * 8) = *(const uint4*)tmp;
  }
}

// ============================================================
// Output projection: d_out[m,n] = Oa[m,:] . Wo[n,:], fp32 row-major out
// ============================================================
__global__ __launch_bounds__(256) void gemm_out(
    const unsigned short* __restrict__ Oa,
    const unsigned short* __restrict__ Woh,
    float* __restrict__ out) {
  __shared__ unsigned short As[128 * 32];
  __shared__ unsigned short Bs[128 * 32];
  const int tid = threadIdx.x;
  const int w = tid >> 6, l = tid & 63;
  const int quad = l >> 4, l15 = l & 15;
  const int m0 = blockIdx.x * 128;
  const int n0 = blockIdx.y * 128;

  f32x4 acc[4][4] = {};
  const int lrow = l >> 2;
  const int lcol = (l & 3) * 8;
  const int wm = (w >> 1) * 64, wn = (w & 1) * 64;

  for (int kk = 0; kk < 512; kk += 32) {
#pragma unroll
    for (int i = 0; i < 2; ++i) {
      int row = w * 32 + i * 16 + lrow;
      gload_lds16(Oa + (size_t)(m0 + row) * 512 + kk + lcol, &As[row * 32 + lcol]);
      gload_lds16(Woh + (size_t)(n0 + row) * 512 + kk + lcol, &Bs[row * 32 + lcol]);
    }
    __syncthreads();
    short8 af[4], bf[4];
#pragma unroll
    for (int t = 0; t < 4; ++t)
      af[t] = *(const short8*)&As[(wm + t * 16 + l15) * 32 + quad * 8];
#pragma unroll
    for (int t = 0; t < 4; ++t)
      bf[t] = *(const short8*)&Bs[(wn + t * 16 + l15) * 32 + quad * 8];
#pragma unroll
    for (int mt = 0; mt < 4; ++mt)
#pragma unroll
      for (int nt = 0; nt < 4; ++nt)
        acc[mt][nt] = MFMA16(af[mt], bf[nt], acc[mt][nt]);
    __syncthreads();
  }
#pragma unroll
  for (int mt = 0; mt < 4; ++mt)
#pragma unroll
    for (int nt = 0; nt < 4; ++nt)
#pragma unroll
      for (int r = 0; r < 4; ++r) {
        int m  = m0 + wm + mt * 16 + quad * 4 + r;
        int nn = n0 + wn + nt * 16 + l15;
        out[(size_t)m * 512 + nn] = acc[mt][nt][r];
      }
}

// ============================================================
// Flash attention v2: 1 block = 64 Q-rows of one (b,h), 4 waves x 16 rows.
// Q fragments in registers (no Qs LDS). K/V staged via global_load_lds
// (width 16) with XOR-swizzled columns; fragment reads un-swizzle.
// LDS ~26KB -> 4 blocks/CU resident (grid 1024). exp2-domain softmax.
// ============================================================
__global__ __launch_bounds__(256, 4) void attn(
    const unsigned short* __restrict__ Qp,
    const unsigned short* __restrict__ Kp,
    const unsigned short* __restrict__ Vt,
    const int* __restrict__ mask,
    unsigned short* __restrict__ Oa) {
  __shared__ unsigned short Ks[64 * 64];   // [key][hd], col-blocks XOR-swizzled
  __shared__ unsigned short Vs[64 * 64];   // [hd][key], col-blocks XOR-swizzled
  __shared__ unsigned short Ps[4][16 * 72];
  __shared__ float bias_s[64];

  const int tid = threadIdx.x;
  const int w = tid >> 6, l = tid & 63;
  const int quad = l >> 4, l15 = l & 15;
  const int bid = blockIdx.x;
  const int bh = bid & 31;      // same bh -> same XCD (bid%8 == bh%8)
  const int qt = bid >> 5;      // 0..31, 64 q-rows per block
  const int b = bh >> 3, h = bh & 7;

  // ---- Q fragments from global, held in registers all kernel ----
  const int qrow = qt * 64 + w * 16 + l15;
  short8 aq[2];
#pragma unroll
  for (int k2 = 0; k2 < 2; ++k2)
    aq[k2] = *(const short8*)(Qp + ((size_t)bh * Qlen + qrow) * HDim + (k2 * 4 + quad) * 8);

  f32x4 o[4] = {};
  float m_run[4], l_run[4];
#pragma unroll
  for (int r = 0; r < 4; ++r) { m_run[r] = -1.0e6f; l_run[r] = 0.f; }

  constexpr float C1    = 0.125f * 1.4426950408889634f;  // scale*log2e
  constexpr float BIAS2 = -43000.0f;                     // ~ -30000*log2e

  for (int kt = 0; kt < Klen / 64; ++kt) {
    __syncthreads();   // prev tile's LDS reads done
#pragma unroll
    for (int i = 0; i < 2; ++i) {
      int g = i * 256 + tid;
      int row = g >> 3, c8 = g & 7;
      int sb = ((c8 ^ (row & 7))) * 8;      // swizzled source col-block
      gload_lds16(Kp + ((size_t)bh * Klen + kt * 64 + row) * HDim + sb, &Ks[g * 8]);
      gload_lds16(Vt + ((size_t)bh * HDim + row) * Klen + kt * 64 + sb, &Vs[g * 8]);
    }
    if (tid < 64)
      bias_s[tid] = (mask[b * Klen + kt * 64 + tid] == 0) ? BIAS2 : 0.f;
    __syncthreads();   // drains global_load_lds (vmcnt) + bias visible

    // ---- S = Q K^T : 16 q-rows x 64 keys (4 ct tiles) ----
    f32x4 sv[4];
#pragma unroll
    for (int ct = 0; ct < 4; ++ct) {
      const int x = l15 & 7;
      const short8 bk0 = *(const short8*)&Ks[(ct * 16 + l15) * 64 + (quad ^ x) * 8];
      const short8 bk1 = *(const short8*)&Ks[(ct * 16 + l15) * 64 + ((4 + quad) ^ x) * 8];
      f32x4 a = {};
      a = MFMA16(aq[0], bk0, a);
      a = MFMA16(aq[1], bk1, a);
      sv[ct] = a;
    }
    float bb4[4];
#pragma unroll
    for (int ct = 0; ct < 4; ++ct) bb4[ct] = bias_s[ct * 16 + l15];

    // ---- online softmax in exp2 domain (row = quad*4+r, col = ct*16+l15) ----
#pragma unroll
    for (int ct = 0; ct < 4; ++ct)
#pragma unroll
      for (int r = 0; r < 4; ++r)
        sv[ct][r] = sv[ct][r] * C1 + bb4[ct];
#pragma unroll
    for (int r = 0; r < 4; ++r) {
      float mx = fmaxf(fmaxf(sv[0][r], sv[1][r]), fmaxf(sv[2][r], sv[3][r]));
#pragma unroll
      for (int off = 1; off < 16; off <<= 1)
        mx = fmaxf(mx, __shfl_xor(mx, off, 16));
      float mnew  = fmaxf(m_run[r], mx);
      float alpha = exp2f(m_run[r] - mnew);
      float rs = 0.f;
#pragma unroll
      for (int ct = 0; ct < 4; ++ct) {
        float p = exp2f(sv[ct][r] - mnew);
        sv[ct][r] = p;
        rs += p;
      }
#pragma unroll
      for (int off = 1; off < 16; off <<= 1)
        rs += __shfl_xor(rs, off, 16);
      l_run[r] = l_run[r] * alpha + rs;
      m_run[r] = mnew;
#pragma unroll
      for (int ctd = 0; ctd < 4; ++ctd) o[ctd][r] *= alpha;
    }
    // P (C-layout) -> wave-private LDS, re-read in A-layout
#pragma unroll
    for (int ct = 0; ct < 4; ++ct)
#pragma unroll
      for (int r = 0; r < 4; ++r)
        Ps[w][(quad * 4 + r) * 72 + ct * 16 + l15] = f2h(sv[ct][r]);

    // ---- O += P V (within-wave LDS ordering; no barrier needed) ----
    const short8 ap0 = *(const short8*)&Ps[w][l15 * 72 + quad * 8];
    const short8 ap1 = *(const short8*)&Ps[w][l15 * 72 + (4 + quad) * 8];
#pragma unroll
    for (int ctd = 0; ctd < 4; ++ctd) {
      const int x = l15 & 7;
      const short8 bv0 = *(const short8*)&Vs[(ctd * 16 + l15) * 64 + (quad ^ x) * 8];
      const short8 bv1 = *(const short8*)&Vs[(ctd * 16 + l15) * 64 + ((4 + quad) ^ x) * 8];
      o[ctd] = MFMA16(ap0, bv0, o[ctd]);
      o[ctd] = MFMA16(ap1, bv1, o[ctd]);
    }
  }

  // ---- epilogue: Oa (B, Q, D) fp16, feature = h*64 + d ----
  float rl[4];
#pragma unroll
  for (int r = 0; r < 4; ++r) rl[r] = 1.0f / l_run[r];
#pragma unroll
  for (int ctd = 0; ctd < 4; ++ctd)
#pragma unroll
    for (int r = 0; r < 4; ++r) {
      int qq = qt * 64 + w * 16 + quad * 4 + r;
      Oa[((size_t)(b * Qlen) + qq) * Dm + h * 64 + ctd * 16 + l15] =
          f2h(o[ctd][r] * rl[r]);
    }
}

extern "C" void kernel_launch(void* const* d_in, const int* in_sizes, int n_in,
                              void* d_out, int out_size, void* d_ws, size_t ws_size,
                              hipStream_t stream) {
  const float* q  = (const float*)d_in[0];
  const float* k  = (const float*)d_in[1];
  const float* v  = (const float*)d_in[2];
  const float* Wq = (const float*)d_in[3];
  const float* Wk = (const float*)d_in[4];
  const float* Wv = (const float*)d_in[5];
  const float* Wo = (const float*)d_in[6];
  const int*  msk = (const int*)d_in[7];
  float* out = (float*)d_out;

  char* ws = (char*)d_ws;
  const size_t SEG  = (size_t)Bc * Hh * Qlen * HDim * sizeof(unsigned short); // 8 MB
  const size_t WSEG = (size_t)Dm * Dm * sizeof(unsigned short);               // 0.5 MB
  unsigned short* Qp  = (unsigned short*)(ws);
  unsigned short* Kp  = (unsigned short*)(ws + SEG);
  unsigned short* Vp  = (unsigned short*)(ws + 2 * SEG);
  unsigned short* Vt  = (unsigned short*)(ws + 3 * SEG);
  unsigned short* Oa  = Vp;  // Vp dead after transpose_v; reuse for Oa
  unsigned short* Wqh = (unsigned short*)(ws + 4 * SEG);
  unsigned short* Wkh = (unsigned short*)(ws + 4 * SEG + WSEG);
  unsigned short* Wvh = (unsigned short*)(ws + 4 * SEG + 2 * WSEG);
  unsigned short* Woh = (unsigned short*)(ws + 4 * SEG + 3 * WSEG);

  const int wn = Dm * Dm;                       // 262144
  const int cblk = wn / (256 * 4);              // 256 blocks
  hipLaunchKernelGGL(cvt_f32_f16, dim3(cblk), dim3(256), 0, stream, Wq, Wqh, wn);
  hipLaunchKernelGGL(cvt_f32_f16, dim3(cblk), dim3(256), 0, stream, Wk, Wkh, wn);
  hipLaunchKernelGGL(cvt_f32_f16, dim3(cblk), dim3(256), 0, stream, Wv, Wvh, wn);
  hipLaunchKernelGGL(cvt_f32_f16, dim3(cblk), dim3(256), 0, stream, Wo, Woh, wn);

  hipLaunchKernelGGL(gemm_qkv, dim3(64, 12), dim3(256), 0, stream,
                     q, k, v, Wqh, Wkh, Wvh, Qp, Kp, Vp);
  hipLaunchKernelGGL(transpose_v, dim3(32, 32), dim3(256), 0, stream, Vp, Vt);
  hipLaunchKernelGGL(attn, dim3(1024), dim3(256), 0, stream, Qp, Kp, Vt, msk, Oa);
  hipLaunchKernelGGL(gemm_out, dim3(64, 4), dim3(256), 0, stream, Oa, Woh, out);
}

// Round 6
// 240.646 us; speedup vs baseline: 1.1960x; 1.1250x over previous
//
#include <hip/hip_runtime.h>

// ---- problem constants ----
constexpr int Bc   = 4;
constexpr int Qlen = 2048;
constexpr int Klen = 2048;
constexpr int Dm   = 512;
constexpr int Hh   = 8;
constexpr int HDim = 64;

typedef __attribute__((ext_vector_type(8))) short short8;       // 8x16-bit storage
typedef __attribute__((ext_vector_type(8))) _Float16 half8;     // fp16 MFMA frag
typedef __attribute__((ext_vector_type(4))) float f32x4;

__device__ __forceinline__ f32x4 MFMA16(short8 a, short8 b, f32x4 c) {
  return __builtin_amdgcn_mfma_f32_16x16x32_f16(
      __builtin_bit_cast(half8, a), __builtin_bit_cast(half8, b), c, 0, 0, 0);
}

__device__ __forceinline__ void gload_lds16(const void* g, void* l) {
  __builtin_amdgcn_global_load_lds(
      (const __attribute__((address_space(1))) void*)g,
      (__attribute__((address_space(3))) void*)l, 16, 0, 0);
}

__device__ __forceinline__ unsigned short f2h(float f) {   // f32 -> fp16 RNE
  _Float16 h = (_Float16)f;
  return __builtin_bit_cast(unsigned short, h);
}

// ---- DPP 16-lane-row butterfly all-reduce (xor1, xor2, xor7-combine, xor15) ----
template <int CTRL>
__device__ __forceinline__ float dpp_f(float x) {
  int i = __builtin_bit_cast(int, x);
  int y = __builtin_amdgcn_update_dpp(i, i, CTRL, 0xF, 0xF, true);
  return __builtin_bit_cast(float, y);
}
__device__ __forceinline__ float rowmax16(float x) {
  x = fmaxf(x, dpp_f<0xB1>(x));    // quad_perm [1,0,3,2]  (xor 1)
  x = fmaxf(x, dpp_f<0x4E>(x));    // quad_perm [2,3,0,1]  (xor 2)
  x = fmaxf(x, dpp_f<0x141>(x));   // row_half_mirror      (xor 7)
  x = fmaxf(x, dpp_f<0x140>(x));   // row_mirror           (xor 15)
  return x;
}
__device__ __forceinline__ float rowsum16(float x) {
  x += dpp_f<0xB1>(x);
  x += dpp_f<0x4E>(x);
  x += dpp_f<0x141>(x);
  x += dpp_f<0x140>(x);
  return x;
}

// ============================================================
// Fused f32 -> fp16 conversion of the 4 weight matrices (1 launch)
// ============================================================
__global__ __launch_bounds__(256) void cvt4(
    const float* __restrict__ s0, const float* __restrict__ s1,
    const float* __restrict__ s2, const float* __restrict__ s3,
    unsigned short* __restrict__ o0, unsigned short* __restrict__ o1,
    unsigned short* __restrict__ o2, unsigned short* __restrict__ o3) {
  const int seg = blockIdx.y;
  const float* s = (seg == 0) ? s0 : (seg == 1) ? s1 : (seg == 2) ? s2 : s3;
  unsigned short* o = (seg == 0) ? o0 : (seg == 1) ? o1 : (seg == 2) ? o2 : o3;
  int i = (blockIdx.x * 256 + threadIdx.x) * 4;
  float4 x = *(const float4*)(s + i);
  unsigned short t[4] = {f2h(x.x), f2h(x.y), f2h(x.z), f2h(x.w)};
  *(uint2*)(o + i) = *(const uint2*)t;
}

// ============================================================
// Fused QKV projection: C[m,n] = X[m,:] . W[n,:]  (X @ W^T)
// X fp32 (converted to fp16 in-flight); W pre-converted fp16.
// ============================================================
__global__ __launch_bounds__(256) void gemm_qkv(
    const float* __restrict__ q_in,
    const float* __restrict__ k_in,
    const float* __restrict__ v_in,
    const unsigned short* __restrict__ Wqh,
    const unsigned short* __restrict__ Wkh,
    const unsigned short* __restrict__ Wvh,
    unsigned short* __restrict__ Qp,
    unsigned short* __restrict__ Kp,
    unsigned short* __restrict__ Vp) {
  __shared__ unsigned short As[128 * 32];
  __shared__ unsigned short Bs[128 * 32];
  const int tid = threadIdx.x;
  const int w = tid >> 6, l = tid & 63;
  const int quad = l >> 4, l15 = l & 15;
  const int m0 = blockIdx.x * 128;
  const int n0 = blockIdx.y * 128;
  const int seg = n0 >> 9;
  const int f0  = n0 & 511;
  const float* A = (seg == 0) ? q_in : (seg == 1) ? k_in : v_in;
  const unsigned short* W = (seg == 0) ? Wqh : (seg == 1) ? Wkh : Wvh;
  unsigned short* dst = (seg == 0) ? Qp : (seg == 1) ? Kp : Vp;

  f32x4 acc[4][4] = {};
  const int lrow = l >> 2;
  const int lcol = (l & 3) * 8;
  const int wm = (w >> 1) * 64, wn = (w & 1) * 64;

  for (int kk = 0; kk < 512; kk += 32) {
#pragma unroll
    for (int i = 0; i < 2; ++i) {
      int row = w * 32 + i * 16 + lrow;
      const float* ap = A + (size_t)(m0 + row) * 512 + kk + lcol;
      float4 x0 = *(const float4*)(ap);
      float4 x1 = *(const float4*)(ap + 4);
      union { short8 v; unsigned short u[8]; } t;
      t.u[0] = f2h(x0.x); t.u[1] = f2h(x0.y);
      t.u[2] = f2h(x0.z); t.u[3] = f2h(x0.w);
      t.u[4] = f2h(x1.x); t.u[5] = f2h(x1.y);
      t.u[6] = f2h(x1.z); t.u[7] = f2h(x1.w);
      *(short8*)&As[row * 32 + lcol] = t.v;
      gload_lds16(W + (size_t)(f0 + row) * 512 + kk + lcol, &Bs[row * 32 + lcol]);
    }
    __syncthreads();
    short8 af[4], bf[4];
#pragma unroll
    for (int t = 0; t < 4; ++t)
      af[t] = *(const short8*)&As[(wm + t * 16 + l15) * 32 + quad * 8];
#pragma unroll
    for (int t = 0; t < 4; ++t)
      bf[t] = *(const short8*)&Bs[(wn + t * 16 + l15) * 32 + quad * 8];
#pragma unroll
    for (int mt = 0; mt < 4; ++mt)
#pragma unroll
      for (int nt = 0; nt < 4; ++nt)
        acc[mt][nt] = MFMA16(af[mt], bf[nt], acc[mt][nt]);
    __syncthreads();
  }
#pragma unroll
  for (int mt = 0; mt < 4; ++mt)
#pragma unroll
    for (int nt = 0; nt < 4; ++nt)
#pragma unroll
      for (int r = 0; r < 4; ++r) {
        int m  = m0 + wm + mt * 16 + quad * 4 + r;
        int nn = f0 + wn + nt * 16 + l15;
        int b = m >> 11, qq = m & 2047;
        int h = nn >> 6, hd = nn & 63;
        dst[(((size_t)(b * Hh + h)) * Qlen + qq) * HDim + hd] = f2h(acc[mt][nt][r]);
      }
}

// ============================================================
// V transpose: Vp (B,H,K,HD) -> Vt (B,H,HD,K), 64x64 tiles via LDS
// ============================================================
__global__ __launch_bounds__(256) void transpose_v(
    const unsigned short* __restrict__ Vp, unsigned short* __restrict__ Vt) {
  __shared__ unsigned short t[64 * 72];
  const int bh = blockIdx.y, jt = blockIdx.x;
  const int tid = threadIdx.x;
#pragma unroll
  for (int i = 0; i < 2; ++i) {
    int g = i * 256 + tid;
    int j = g >> 3, c8 = g & 7;
    *(uint4*)&t[j * 72 + c8 * 8] =
        *(const uint4*)(Vp + ((size_t)bh * Klen + jt * 64 + j) * 64 + c8 * 8);
  }
  __syncthreads();
#pragma unroll
  for (int i = 0; i < 2; ++i) {
    int g = i * 256 + tid;
    int d = g >> 3, j8 = g & 7;
    unsigned short tmp[8];
#pragma unroll
    for (int kx = 0; kx < 8; ++kx) tmp[kx] = t[(j8 * 8 + kx) * 72 + d];
    *(uint4*)(Vt + ((size_t)bh * HDim + d) * Klen + jt * 64 + j8 * 8) = *(const uint4*)tmp;
  }
}

// ============================================================
// Output projection: d_out[m,n] = Oa[m,:] . Wo[n,:], fp32 row-major out
// ============================================================
__global__ __launch_bounds__(256) void gemm_out(
    const unsigned short* __restrict__ Oa,
    const unsigned short* __restrict__ Woh,
    float* __restrict__ out) {
  __shared__ unsigned short As[128 * 32];
  __shared__ unsigned short Bs[128 * 32];
  const int tid = threadIdx.x;
  const int w = tid >> 6, l = tid & 63;
  const int quad = l >> 4, l15 = l & 15;
  const int m0 = blockIdx.x * 128;
  const int n0 = blockIdx.y * 128;

  f32x4 acc[4][4] = {};
  const int lrow = l >> 2;
  const int lcol = (l & 3) * 8;
  const int wm = (w >> 1) * 64, wn = (w & 1) * 64;

  for (int kk = 0; kk < 512; kk += 32) {
#pragma unroll
    for (int i = 0; i < 2; ++i) {
      int row = w * 32 + i * 16 + lrow;
      gload_lds16(Oa + (size_t)(m0 + row) * 512 + kk + lcol, &As[row * 32 + lcol]);
      gload_lds16(Woh + (size_t)(n0 + row) * 512 + kk + lcol, &Bs[row * 32 + lcol]);
    }
    __syncthreads();
    short8 af[4], bf[4];
#pragma unroll
    for (int t = 0; t < 4; ++t)
      af[t] = *(const short8*)&As[(wm + t * 16 + l15) * 32 + quad * 8];
#pragma unroll
    for (int t = 0; t < 4; ++t)
      bf[t] = *(const short8*)&Bs[(wn + t * 16 + l15) * 32 + quad * 8];
#pragma unroll
    for (int mt = 0; mt < 4; ++mt)
#pragma unroll
      for (int nt = 0; nt < 4; ++nt)
        acc[mt][nt] = MFMA16(af[mt], bf[nt], acc[mt][nt]);
    __syncthreads();
  }
#pragma unroll
  for (int mt = 0; mt < 4; ++mt)
#pragma unroll
    for (int nt = 0; nt < 4; ++nt)
#pragma unroll
      for (int r = 0; r < 4; ++r) {
        int m  = m0 + wm + mt * 16 + quad * 4 + r;
        int nn = n0 + wn + nt * 16 + l15;
        out[(size_t)m * 512 + nn] = acc[mt][nt][r];
      }
}

// ============================================================
// Flash attention v3: 64 Q-rows/block, 4 waves x 16 rows.
// Softmax trims: DPP max (no ds_swizzle), fully deferred sum
// (no cross-lane in loop), mask prefetched to registers.
// ============================================================
__global__ __launch_bounds__(256, 4) void attn(
    const unsigned short* __restrict__ Qp,
    const unsigned short* __restrict__ Kp,
    const unsigned short* __restrict__ Vt,
    const int* __restrict__ mask,
    unsigned short* __restrict__ Oa) {
  __shared__ unsigned short Ks[64 * 64];   // [key][hd], col-blocks XOR-swizzled
  __shared__ unsigned short Vs[64 * 64];   // [hd][key], col-blocks XOR-swizzled
  __shared__ unsigned short Ps[4][16 * 72];

  const int tid = threadIdx.x;
  const int w = tid >> 6, l = tid & 63;
  const int quad = l >> 4, l15 = l & 15;
  const int bid = blockIdx.x;
  const int bh = bid & 31;      // same bh -> same XCD (bid%8 == bh%8)
  const int qt = bid >> 5;      // 64 q-rows per block
  const int b = bh >> 3, h = bh & 7;

  // ---- Q fragments in registers for the whole kernel ----
  const int qrow = qt * 64 + w * 16 + l15;
  short8 aq[2];
#pragma unroll
  for (int k2 = 0; k2 < 2; ++k2)
    aq[k2] = *(const short8*)(Qp + ((size_t)bh * Qlen + qrow) * HDim + (k2 * 4 + quad) * 8);

  f32x4 o[4] = {};
  float m_run[4], l_acc[4];
#pragma unroll
  for (int r = 0; r < 4; ++r) { m_run[r] = -1.0e6f; l_acc[r] = 0.f; }

  constexpr float C1    = 0.125f * 1.4426950408889634f;  // scale*log2e
  constexpr float BIAS2 = -43000.0f;                     // exp2 -> exact 0

  // ---- mask prefetch for tile 0 ----
  const int* mrow = mask + b * Klen;
  int mb[4];
#pragma unroll
  for (int ct = 0; ct < 4; ++ct) mb[ct] = mrow[ct * 16 + l15];

  for (int kt = 0; kt < Klen / 64; ++kt) {
    __syncthreads();   // prev tile's LDS reads done
#pragma unroll
    for (int i = 0; i < 2; ++i) {
      int g = i * 256 + tid;
      int row = g >> 3, c8 = g & 7;
      int sb = (c8 ^ (row & 7)) * 8;      // swizzled source col-block
      gload_lds16(Kp + ((size_t)bh * Klen + kt * 64 + row) * HDim + sb, &Ks[g * 8]);
      gload_lds16(Vt + ((size_t)bh * HDim + row) * Klen + kt * 64 + sb, &Vs[g * 8]);
    }
    // bias from the prefetched mask regs; then prefetch next tile's mask
    float bb4[4];
#pragma unroll
    for (int ct = 0; ct < 4; ++ct) bb4[ct] = (mb[ct] == 0) ? BIAS2 : 0.f;
    if (kt + 1 < Klen / 64) {
#pragma unroll
      for (int ct = 0; ct < 4; ++ct) mb[ct] = mrow[(kt + 1) * 64 + ct * 16 + l15];
    }
    __syncthreads();   // drains global_load_lds (vmcnt)

    // ---- S = Q K^T : 16 q-rows x 64 keys ----
    f32x4 sv[4];
#pragma unroll
    for (int ct = 0; ct < 4; ++ct) {
      const int x = l15 & 7;
      const short8 bk0 = *(const short8*)&Ks[(ct * 16 + l15) * 64 + (quad ^ x) * 8];
      const short8 bk1 = *(const short8*)&Ks[(ct * 16 + l15) * 64 + ((4 + quad) ^ x) * 8];
      f32x4 a = {};
      a = MFMA16(aq[0], bk0, a);
      a = MFMA16(aq[1], bk1, a);
      sv[ct] = a;
    }

    // ---- online softmax, exp2 domain; no cross-lane sum in loop ----
#pragma unroll
    for (int ct = 0; ct < 4; ++ct)
#pragma unroll
      for (int r = 0; r < 4; ++r)
        sv[ct][r] = sv[ct][r] * C1 + bb4[ct];
#pragma unroll
    for (int r = 0; r < 4; ++r) {
      float mx = fmaxf(fmaxf(sv[0][r], sv[1][r]), fmaxf(sv[2][r], sv[3][r]));
      mx = rowmax16(mx);                       // 4 DPP ops, VALU-only
      float mnew  = fmaxf(m_run[r], mx);
      float alpha = exp2f(m_run[r] - mnew);
      float p0 = exp2f(sv[0][r] - mnew);
      float p1 = exp2f(sv[1][r] - mnew);
      float p2 = exp2f(sv[2][r] - mnew);
      float p3 = exp2f(sv[3][r] - mnew);
      sv[0][r] = p0; sv[1][r] = p1; sv[2][r] = p2; sv[3][r] = p3;
      l_acc[r] = l_acc[r] * alpha + ((p0 + p1) + (p2 + p3));  // per-lane partial
      m_run[r] = mnew;
#pragma unroll
      for (int ctd = 0; ctd < 4; ++ctd) o[ctd][r] *= alpha;
    }
    // P (C-layout) -> wave-private LDS, re-read in A-layout
#pragma unroll
    for (int ct = 0; ct < 4; ++ct)
#pragma unroll
      for (int r = 0; r < 4; ++r)
        Ps[w][(quad * 4 + r) * 72 + ct * 16 + l15] = f2h(sv[ct][r]);

    // ---- O += P V (within-wave LDS ordering) ----
    const short8 ap0 = *(const short8*)&Ps[w][l15 * 72 + quad * 8];
    const short8 ap1 = *(const short8*)&Ps[w][l15 * 72 + (4 + quad) * 8];
#pragma unroll
    for (int ctd = 0; ctd < 4; ++ctd) {
      const int x = l15 & 7;
      const short8 bv0 = *(const short8*)&Vs[(ctd * 16 + l15) * 64 + (quad ^ x) * 8];
      const short8 bv1 = *(const short8*)&Vs[(ctd * 16 + l15) * 64 + ((4 + quad) ^ x) * 8];
      o[ctd] = MFMA16(ap0, bv0, o[ctd]);
      o[ctd] = MFMA16(ap1, bv1, o[ctd]);
    }
  }

  // ---- epilogue: one cross-lane sum reduction, then store ----
  float rl[4];
#pragma unroll
  for (int r = 0; r < 4; ++r) rl[r] = 1.0f / rowsum16(l_acc[r]);
#pragma unroll
  for (int ctd = 0; ctd < 4; ++ctd)
#pragma unroll
    for (int r = 0; r < 4; ++r) {
      int qq = qt * 64 + w * 16 + quad * 4 + r;
      Oa[((size_t)(b * Qlen) + qq) * Dm + h * 64 + ctd * 16 + l15] =
          f2h(o[ctd][r] * rl[r]);
    }
}

extern "C" void kernel_launch(void* const* d_in, const int* in_sizes, int n_in,
                              void* d_out, int out_size, void* d_ws, size_t ws_size,
                              hipStream_t stream) {
  const float* q  = (const float*)d_in[0];
  const float* k  = (const float*)d_in[1];
  const float* v  = (const float*)d_in[2];
  const float* Wq = (const float*)d_in[3];
  const float* Wk = (const float*)d_in[4];
  const float* Wv = (const float*)d_in[5];
  const float* Wo = (const float*)d_in[6];
  const int*  msk = (const int*)d_in[7];
  float* out = (float*)d_out;

  char* ws = (char*)d_ws;
  const size_t SEG  = (size_t)Bc * Hh * Qlen * HDim * sizeof(unsigned short); // 8 MB
  const size_t WSEG = (size_t)Dm * Dm * sizeof(unsigned short);               // 0.5 MB
  unsigned short* Qp  = (unsigned short*)(ws);
  unsigned short* Kp  = (unsigned short*)(ws + SEG);
  unsigned short* Vp  = (unsigned short*)(ws + 2 * SEG);
  unsigned short* Vt  = (unsigned short*)(ws + 3 * SEG);
  unsigned short* Oa  = Vp;  // Vp dead after transpose_v; reuse for Oa
  unsigned short* Wqh = (unsigned short*)(ws + 4 * SEG);
  unsigned short* Wkh = (unsigned short*)(ws + 4 * SEG + WSEG);
  unsigned short* Wvh = (unsigned short*)(ws + 4 * SEG + 2 * WSEG);
  unsigned short* Woh = (unsigned short*)(ws + 4 * SEG + 3 * WSEG);

  const int wn = Dm * Dm;                       // 262144
  hipLaunchKernelGGL(cvt4, dim3(wn / 1024, 4), dim3(256), 0, stream,
                     Wq, Wk, Wv, Wo, Wqh, Wkh, Wvh, Woh);

  hipLaunchKernelGGL(gemm_qkv, dim3(64, 12), dim3(256), 0, stream,
                     q, k, v, Wqh, Wkh, Wvh, Qp, Kp, Vp);
  hipLaunchKernelGGL(transpose_v, dim3(32, 32), dim3(256), 0, stream, Vp, Vt);
  hipLaunchKernelGGL(attn, dim3(1024), dim3(256), 0, stream, Qp, Kp, Vt, msk, Oa);
  hipLaunchKernelGGL(gemm_out, dim3(64, 4), dim3(256), 0, stream, Oa, Woh, out);
}

// Round 8
// 233.945 us; speedup vs baseline: 1.2303x; 1.0286x over previous
//
#include <hip/hip_runtime.h>

// ---- problem constants ----
constexpr int Bc   = 4;
constexpr int Qlen = 2048;
constexpr int Klen = 2048;
constexpr int Dm   = 512;
constexpr int Hh   = 8;
constexpr int HDim = 64;

typedef __attribute__((ext_vector_type(8))) short short8;       // 8x16-bit storage
typedef __attribute__((ext_vector_type(8))) _Float16 half8;     // fp16 MFMA frag
typedef __attribute__((ext_vector_type(2))) __fp16 fp16x2;      // cvt_pkrtz result
typedef __attribute__((ext_vector_type(4))) float f32x4;

__device__ __forceinline__ f32x4 MFMA16(short8 a, short8 b, f32x4 c) {
  return __builtin_amdgcn_mfma_f32_16x16x32_f16(
      __builtin_bit_cast(half8, a), __builtin_bit_cast(half8, b), c, 0, 0, 0);
}

__device__ __forceinline__ void gload_lds16(const void* g, void* l) {
  __builtin_amdgcn_global_load_lds(
      (const __attribute__((address_space(1))) void*)g,
      (__attribute__((address_space(3))) void*)l, 16, 0, 0);
}

__device__ __forceinline__ unsigned short f2h(float f) {   // f32 -> fp16 RNE
  _Float16 h = (_Float16)f;
  return __builtin_bit_cast(unsigned short, h);
}

__device__ __forceinline__ unsigned pk2h(float a, float b) {  // packed f32x2 -> f16x2 (RTZ)
  fp16x2 h = __builtin_amdgcn_cvt_pkrtz(a, b);
  return __builtin_bit_cast(unsigned, h);
}

// ============================================================
// cvt4: f32->fp16 of the 4 weight matrices + mask->f32 bias (seg 4)
// ============================================================
__global__ __launch_bounds__(256) void cvt4(
    const float* __restrict__ s0, const float* __restrict__ s1,
    const float* __restrict__ s2, const float* __restrict__ s3,
    unsigned short* __restrict__ o0, unsigned short* __restrict__ o1,
    unsigned short* __restrict__ o2, unsigned short* __restrict__ o3,
    const int* __restrict__ msk, float* __restrict__ biasf) {
  const int seg = blockIdx.y;
  int i = (blockIdx.x * 256 + threadIdx.x) * 4;
  if (seg < 4) {
    const float* s = (seg == 0) ? s0 : (seg == 1) ? s1 : (seg == 2) ? s2 : s3;
    unsigned short* o = (seg == 0) ? o0 : (seg == 1) ? o1 : (seg == 2) ? o2 : o3;
    float4 x = *(const float4*)(s + i);
    unsigned short t[4] = {f2h(x.x), f2h(x.y), f2h(x.z), f2h(x.w)};
    *(uint2*)(o + i) = *(const uint2*)t;
  } else if (i + 3 < Bc * Klen) {   // mask -> additive exp2-domain bias
    int4 m = *(const int4*)(msk + i);
    float4 bo;
    bo.x = (m.x == 0) ? -60000.0f : 0.0f;
    bo.y = (m.y == 0) ? -60000.0f : 0.0f;
    bo.z = (m.z == 0) ? -60000.0f : 0.0f;
    bo.w = (m.w == 0) ? -60000.0f : 0.0f;
    *(float4*)(biasf + i) = bo;
  }
}

// ============================================================
// Fused QKV projection: C[m,n] = X[m,:] . W[n,:]  (X @ W^T)
// ============================================================
__global__ __launch_bounds__(256) void gemm_qkv(
    const float* __restrict__ q_in,
    const float* __restrict__ k_in,
    const float* __restrict__ v_in,
    const unsigned short* __restrict__ Wqh,
    const unsigned short* __restrict__ Wkh,
    const unsigned short* __restrict__ Wvh,
    unsigned short* __restrict__ Qp,
    unsigned short* __restrict__ Kp,
    unsigned short* __restrict__ Vp) {
  __shared__ unsigned short As[128 * 32];
  __shared__ unsigned short Bs[128 * 32];
  const int tid = threadIdx.x;
  const int w = tid >> 6, l = tid & 63;
  const int quad = l >> 4, l15 = l & 15;
  const int m0 = blockIdx.x * 128;
  const int n0 = blockIdx.y * 128;
  const int seg = n0 >> 9;
  const int f0  = n0 & 511;
  const float* A = (seg == 0) ? q_in : (seg == 1) ? k_in : v_in;
  const unsigned short* W = (seg == 0) ? Wqh : (seg == 1) ? Wkh : Wvh;
  unsigned short* dst = (seg == 0) ? Qp : (seg == 1) ? Kp : Vp;

  f32x4 acc[4][4] = {};
  const int lrow = l >> 2;
  const int lcol = (l & 3) * 8;
  const int wm = (w >> 1) * 64, wn = (w & 1) * 64;

  for (int kk = 0; kk < 512; kk += 32) {
#pragma unroll
    for (int i = 0; i < 2; ++i) {
      int row = w * 32 + i * 16 + lrow;
      const float* ap = A + (size_t)(m0 + row) * 512 + kk + lcol;
      float4 x0 = *(const float4*)(ap);
      float4 x1 = *(const float4*)(ap + 4);
      unsigned t[4] = {pk2h(x0.x, x0.y), pk2h(x0.z, x0.w),
                       pk2h(x1.x, x1.y), pk2h(x1.z, x1.w)};
      *(uint4*)&As[row * 32 + lcol] = *(const uint4*)t;
      gload_lds16(W + (size_t)(f0 + row) * 512 + kk + lcol, &Bs[row * 32 + lcol]);
    }
    __syncthreads();
    short8 af[4], bf[4];
#pragma unroll
    for (int t = 0; t < 4; ++t)
      af[t] = *(const short8*)&As[(wm + t * 16 + l15) * 32 + quad * 8];
#pragma unroll
    for (int t = 0; t < 4; ++t)
      bf[t] = *(const short8*)&Bs[(wn + t * 16 + l15) * 32 + quad * 8];
#pragma unroll
    for (int mt = 0; mt < 4; ++mt)
#pragma unroll
      for (int nt = 0; nt < 4; ++nt)
        acc[mt][nt] = MFMA16(af[mt], bf[nt], acc[mt][nt]);
    __syncthreads();
  }
#pragma unroll
  for (int mt = 0; mt < 4; ++mt)
#pragma unroll
    for (int nt = 0; nt < 4; ++nt)
#pragma unroll
      for (int r = 0; r < 4; ++r) {
        int m  = m0 + wm + mt * 16 + quad * 4 + r;
        int nn = f0 + wn + nt * 16 + l15;
        int b = m >> 11, qq = m & 2047;
        int h = nn >> 6, hd = nn & 63;
        dst[(((size_t)(b * Hh + h)) * Qlen + qq) * HDim + hd] = f2h(acc[mt][nt][r]);
      }
}

// ============================================================
// V transpose: Vp (B,H,K,HD) -> Vt (B,H,HD,K), 64x64 tiles via LDS
// ============================================================
__global__ __launch_bounds__(256) void transpose_v(
    const unsigned short* __restrict__ Vp, unsigned short* __restrict__ Vt) {
  __shared__ unsigned short t[64 * 72];
  const int bh = blockIdx.y, jt = blockIdx.x;
  const int tid = threadIdx.x;
#pragma unroll
  for (int i = 0; i < 2; ++i) {
    int g = i * 256 + tid;
    int j = g >> 3, c8 = g & 7;
    *(uint4*)&t[j * 72 + c8 * 8] =
        *(const uint4*)(Vp + ((size_t)bh * Klen + jt * 64 + j) * 64 + c8 * 8);
  }
  __syncthreads();
#pragma unroll
  for (int i = 0; i < 2; ++i) {
    int g = i * 256 + tid;
    int d = g >> 3, j8 = g & 7;
    unsigned short tmp[8];
#pragma unroll
    for (int kx = 0; kx < 8; ++kx) tmp[kx] = t[(j8 * 8 + kx) * 72 + d];
    *(uint4*)(Vt + ((size_t)bh * HDim + d) * Klen + jt * 64 + j8 * 8) = *(const uint4*)tmp;
  }
}

// ============================================================
// Output projection: d_out[m,n] = Oa[m,:] . Wo[n,:], fp32 row-major out
// ============================================================
__global__ __launch_bounds__(256) void gemm_out(
    const unsigned short* __restrict__ Oa,
    const unsigned short* __restrict__ Woh,
    float* __restrict__ out) {
  __shared__ unsigned short As[128 * 32];
  __shared__ unsigned short Bs[128 * 32];
  const int tid = threadIdx.x;
  const int w = tid >> 6, l = tid & 63;
  const int quad = l >> 4, l15 = l & 15;
  const int m0 = blockIdx.x * 128;
  const int n0 = blockIdx.y * 128;

  f32x4 acc[4][4] = {};
  const int lrow = l >> 2;
  const int lcol = (l & 3) * 8;
  const int wm = (w >> 1) * 64, wn = (w & 1) * 64;

  for (int kk = 0; kk < 512; kk += 32) {
#pragma unroll
    for (int i = 0; i < 2; ++i) {
      int row = w * 32 + i * 16 + lrow;
      gload_lds16(Oa + (size_t)(m0 + row) * 512 + kk + lcol, &As[row * 32 + lcol]);
      gload_lds16(Woh + (size_t)(n0 + row) * 512 + kk + lcol, &Bs[row * 32 + lcol]);
    }
    __syncthreads();
    short8 af[4], bf[4];
#pragma unroll
    for (int t = 0; t < 4; ++t)
      af[t] = *(const short8*)&As[(wm + t * 16 + l15) * 32 + quad * 8];
#pragma unroll
    for (int t = 0; t < 4; ++t)
      bf[t] = *(const short8*)&Bs[(wn + t * 16 + l15) * 32 + quad * 8];
#pragma unroll
    for (int mt = 0; mt < 4; ++mt)
#pragma unroll
      for (int nt = 0; nt < 4; ++nt)
        acc[mt][nt] = MFMA16(af[mt], bf[nt], acc[mt][nt]);
    __syncthreads();
  }
#pragma unroll
  for (int mt = 0; mt < 4; ++mt)
#pragma unroll
    for (int nt = 0; nt < 4; ++nt)
#pragma unroll
      for (int r = 0; r < 4; ++r) {
        int m  = m0 + wm + mt * 16 + quad * 4 + r;
        int nn = n0 + wn + nt * 16 + l15;
        out[(size_t)m * 512 + nn] = acc[mt][nt][r];
      }
}

// ============================================================
// Flash attention v4: TRANSPOSED score geometry.
// S^T = mfma(K-frag, Q-frag): each lane owns 16 scores of ONE q-row
// (col = l15) -> softmax = in-lane tree + 2 shuffles; one alpha/exp2
// per lane; P^T packs to 4 ds_write_b64; O accumulated transposed.
// ============================================================
__global__ __launch_bounds__(256, 4) void attn(
    const unsigned short* __restrict__ Qp,
    const unsigned short* __restrict__ Kp,
    const unsigned short* __restrict__ Vt,
    const float* __restrict__ biasf,
    unsigned short* __restrict__ Oa) {
  __shared__ unsigned short Ks[64 * 64];   // [key][hd], col-blocks XOR-swizzled
  __shared__ unsigned short Vs[64 * 64];   // [hd][key], col-blocks XOR-swizzled
  __shared__ unsigned short Ps[4][16 * 72]; // per-wave P: [qrow][key], pad 72

  const int tid = threadIdx.x;
  const int w = tid >> 6, l = tid & 63;
  const int quad = l >> 4, l15 = l & 15;
  const int bid = blockIdx.x;
  const int bh = bid & 31;      // same bh -> same XCD (bid%8 == bh%8)
  const int qt = bid >> 5;      // 64 q-rows per block
  const int b = bh >> 3, h = bh & 7;
  const int x = l15 & 7;        // LDS un-swizzle term

  // ---- Q fragments in registers (B-operand of S^T) ----
  const int qrow = qt * 64 + w * 16 + l15;
  short8 aq[2];
#pragma unroll
  for (int k2 = 0; k2 < 2; ++k2)
    aq[k2] = *(const short8*)(Qp + ((size_t)bh * Qlen + qrow) * HDim + (k2 * 4 + quad) * 8);

  f32x4 o[4] = {};                 // O^T: lane holds 16 d-values of q-row l15
  float m_run = -1.0e6f, l_acc = 0.f;

  constexpr float C1 = 0.125f * 1.4426950408889634f;  // scale*log2e

  const float* brow = biasf + b * Klen;

  for (int kt = 0; kt < Klen / 64; ++kt) {
    __syncthreads();   // prev tile's LDS reads done
#pragma unroll
    for (int i = 0; i < 2; ++i) {
      int g = i * 256 + tid;
      int row = g >> 3, c8 = g & 7;
      int sb = (c8 ^ (row & 7)) * 8;      // swizzled source col-block
      gload_lds16(Kp + ((size_t)bh * Klen + kt * 64 + row) * HDim + sb, &Ks[g * 8]);
      gload_lds16(Vt + ((size_t)bh * HDim + row) * Klen + kt * 64 + sb, &Vs[g * 8]);
    }
    // per-lane bias for its 16 keys (key = ct*16 + quad*4 + r)
    float4 bb[4];
#pragma unroll
    for (int ct = 0; ct < 4; ++ct)
      bb[ct] = *(const float4*)(brow + kt * 64 + ct * 16 + quad * 4);
    __syncthreads();   // drains global_load_lds (vmcnt) + bias in regs

    // ---- S^T = K . Q^T : C/D col = qrow(l15), row = key(quad*4+r) ----
    f32x4 sv[4];
#pragma unroll
    for (int ct = 0; ct < 4; ++ct) {
      const short8 bk0 = *(const short8*)&Ks[(ct * 16 + l15) * 64 + (quad ^ x) * 8];
      const short8 bk1 = *(const short8*)&Ks[(ct * 16 + l15) * 64 + ((4 + quad) ^ x) * 8];
      f32x4 a = {};
      a = MFMA16(bk0, aq[0], a);     // operands swapped: A=K, B=Q
      a = MFMA16(bk1, aq[1], a);
      sv[ct] = a;
    }

    // ---- per-lane softmax (all 16 scores belong to q-row l15) ----
#pragma unroll
    for (int ct = 0; ct < 4; ++ct)
#pragma unroll
      for (int r = 0; r < 4; ++r)
        sv[ct][r] = sv[ct][r] * C1 + bb[ct][r];

    float mx0 = fmaxf(fmaxf(sv[0][0], sv[0][1]), fmaxf(sv[0][2], sv[0][3]));
    float mx1 = fmaxf(fmaxf(sv[1][0], sv[1][1]), fmaxf(sv[1][2], sv[1][3]));
    float mx2 = fmaxf(fmaxf(sv[2][0], sv[2][1]), fmaxf(sv[2][2], sv[2][3]));
    float mx3 = fmaxf(fmaxf(sv[3][0], sv[3][1]), fmaxf(sv[3][2], sv[3][3]));
    float mx = fmaxf(fmaxf(mx0, mx1), fmaxf(mx2, mx3));
    mx = fmaxf(mx, __shfl_xor(mx, 16));   // lanes sharing l15 (same q-row)
    mx = fmaxf(mx, __shfl_xor(mx, 32));
    float mnew  = fmaxf(m_run, mx);
    float alpha = exp2f(m_run - mnew);
    m_run = mnew;

    float ps = 0.f;
#pragma unroll
    for (int ct = 0; ct < 4; ++ct) {
      float p0 = exp2f(sv[ct][0] - mnew);
      float p1 = exp2f(sv[ct][1] - mnew);
      float p2 = exp2f(sv[ct][2] - mnew);
      float p3 = exp2f(sv[ct][3] - mnew);
      sv[ct][0] = p0; sv[ct][1] = p1; sv[ct][2] = p2; sv[ct][3] = p3;
      ps += (p0 + p1) + (p2 + p3);
    }
    l_acc = l_acc * alpha + ps;
#pragma unroll
    for (int ctd = 0; ctd < 4; ++ctd) o[ctd] *= alpha;

    // ---- P^T -> Ps[qrow][key]: 4 consecutive keys pack to b64 ----
#pragma unroll
    for (int ct = 0; ct < 4; ++ct) {
      unsigned pk[2] = {pk2h(sv[ct][0], sv[ct][1]), pk2h(sv[ct][2], sv[ct][3])};
      *(uint2*)&Ps[w][l15 * 72 + ct * 16 + quad * 4] = *(const uint2*)pk;
    }

    // ---- O^T += V^T . P^T (operands swapped; within-wave LDS order) ----
    const short8 ap0 = *(const short8*)&Ps[w][l15 * 72 + quad * 8];        // keys 0..31
    const short8 ap1 = *(const short8*)&Ps[w][l15 * 72 + 32 + quad * 8];   // keys 32..63
#pragma unroll
    for (int ctd = 0; ctd < 4; ++ctd) {
      const short8 bv0 = *(const short8*)&Vs[(ctd * 16 + l15) * 64 + (quad ^ x) * 8];
      const short8 bv1 = *(const short8*)&Vs[(ctd * 16 + l15) * 64 + ((4 + quad) ^ x) * 8];
      o[ctd] = MFMA16(bv0, ap0, o[ctd]);
      o[ctd] = MFMA16(bv1, ap1, o[ctd]);
    }
  }

  // ---- epilogue: lane owns q-row l15; d = ctd*16 + quad*4 + r ----
  float lt = l_acc;
  lt += __shfl_xor(lt, 16);
  lt += __shfl_xor(lt, 32);
  float rl = 1.0f / lt;
  const size_t obase = ((size_t)(b * Qlen) + qrow) * Dm + h * 64;
#pragma unroll
  for (int ctd = 0; ctd < 4; ++ctd) {
    unsigned pk[2] = {pk2h(o[ctd][0] * rl, o[ctd][1] * rl),
                      pk2h(o[ctd][2] * rl, o[ctd][3] * rl)};
    *(uint2*)(Oa + obase + ctd * 16 + quad * 4) = *(const uint2*)pk;
  }
}

extern "C" void kernel_launch(void* const* d_in, const int* in_sizes, int n_in,
                              void* d_out, int out_size, void* d_ws, size_t ws_size,
                              hipStream_t stream) {
  const float* q  = (const float*)d_in[0];
  const float* k  = (const float*)d_in[1];
  const float* v  = (const float*)d_in[2];
  const float* Wq = (const float*)d_in[3];
  const float* Wk = (const float*)d_in[4];
  const float* Wv = (const float*)d_in[5];
  const float* Wo = (const float*)d_in[6];
  const int*  msk = (const int*)d_in[7];
  float* out = (float*)d_out;

  char* ws = (char*)d_ws;
  const size_t SEG  = (size_t)Bc * Hh * Qlen * HDim * sizeof(unsigned short); // 8 MB
  const size_t WSEG = (size_t)Dm * Dm * sizeof(unsigned short);               // 0.5 MB
  unsigned short* Qp  = (unsigned short*)(ws);
  unsigned short* Kp  = (unsigned short*)(ws + SEG);
  unsigned short* Vp  = (unsigned short*)(ws + 2 * SEG);
  unsigned short* Vt  = (unsigned short*)(ws + 3 * SEG);
  unsigned short* Oa  = Vp;  // Vp dead after transpose_v; reuse for Oa
  unsigned short* Wqh = (unsigned short*)(ws + 4 * SEG);
  unsigned short* Wkh = (unsigned short*)(ws + 4 * SEG + WSEG);
  unsigned short* Wvh = (unsigned short*)(ws + 4 * SEG + 2 * WSEG);
  unsigned short* Woh = (unsigned short*)(ws + 4 * SEG + 3 * WSEG);
  float*          Bfs = (float*)(ws + 4 * SEG + 4 * WSEG);  // 32 KB bias

  const int wn = Dm * Dm;                       // 262144
  hipLaunchKernelGGL(cvt4, dim3(wn / 1024, 5), dim3(256), 0, stream,
                     Wq, Wk, Wv, Wo, Wqh, Wkh, Wvh, Woh, msk, Bfs);

  hipLaunchKernelGGL(gemm_qkv, dim3(64, 12), dim3(256), 0, stream,
                     q, k, v, Wqh, Wkh, Wvh, Qp, Kp, Vp);
  hipLaunchKernelGGL(transpose_v, dim3(32, 32), dim3(256), 0, stream, Vp, Vt);
  hipLaunchKernelGGL(attn, dim3(1024), dim3(256), 0, stream, Qp, Kp, Vt, Bfs, Oa);
  hipLaunchKernelGGL(gemm_out, dim3(64, 4), dim3(256), 0, stream, Oa, Woh, out);
}